// Round 7
// baseline (260.198 us; speedup 1.0000x reference)
//
#include <hip/hip_runtime.h>

// ---------------------------------------------------------------------------
// CausalSelfAttention fused pipeline (MI355X / gfx950), round 4b.
// (Rounds 4/5 hit GPU-broker timeouts; static audit found the round-4 merge
// buffer O1[64][33] = 34.5 KB LDS capped occupancy at 2 waves/SIMD, defeating
// the design. Fixed: chunked merge via OS[64][17] (~5 KB total LDS).)
// Changes vs round 3:
//  - k_attn: 2-wave blocks, each wave = alternate 32-key tiles of one 32-row
//    q-tile's window; K/V frags global->reg (no LDS staging, no barriers in
//    main loop); prefetch rotation; setprio; XCD-aligned (b,hk) grouping;
//    chunked in-block (m,l,o) merge. Target 4 waves/SIMD.
//  - GEMMs: m97 2-barrier single-buffer, 128x128 tile, acc[4][4].
// ---------------------------------------------------------------------------

typedef __attribute__((ext_vector_type(8))) short bf16x8;
typedef __attribute__((ext_vector_type(4))) float f32x4;
typedef __attribute__((ext_vector_type(16))) float f32x16;
typedef unsigned short u16;
typedef unsigned int u32;

#define B_ 2
#define T_ 2048
#define C_ 1024
#define NH_ 16
#define NKV_ 4
#define WIN_ 1024
#define M_ (B_*T_)
#define EPS_ 1.1920929e-07f

__device__ __forceinline__ u16 f2bf(float f) {
  u32 u = __float_as_uint(f);
  u32 r = (u + 0x7fffu + ((u >> 16) & 1u)) >> 16;
  return (u16)r;
}
__device__ __forceinline__ float bf2f(u16 h) { return __uint_as_float(((u32)h) << 16); }

__device__ __forceinline__ void gload16(const u16* g, u16* l) {
  __builtin_amdgcn_global_load_lds((const __attribute__((address_space(1))) u32*)g,
                                   (__attribute__((address_space(3))) u32*)l, 16, 0, 0);
}
// byte offset of (row, kgroup-of-8-bf16) under the XOR swizzle; rows are 128B.
#define SWZ(row, kg) ((((row)) << 7) + ((((kg) ^ ((row) & 7))) << 4))
// global elem offset a lane fetches so linear LDS slot (l>>3, l&7) holds swz content
#define SWO(lane) (8 * (((lane) & 7) ^ (((lane) >> 3) & 7)))

// ------------------------------------------------- fused f32->bf16 W convert
__global__ __launch_bounds__(256) void k_convert_all(const float* __restrict__ Wq,
                                                     const float* __restrict__ Wk,
                                                     const float* __restrict__ Wv,
                                                     const float* __restrict__ Wo,
                                                     u16* __restrict__ dst) {
  int i4 = blockIdx.x * 256 + threadIdx.x;
  const float* src; int s0;
  if (i4 < 262144)      { src = Wq; s0 = 0; }
  else if (i4 < 327680) { src = Wk; s0 = 262144; }
  else if (i4 < 393216) { src = Wv; s0 = 327680; }
  else                  { src = Wo; s0 = 393216; }
  float4 v = ((const float4*)src)[i4 - s0];
  ushort4 o;
  o.x = f2bf(v.x); o.y = f2bf(v.y); o.z = f2bf(v.z); o.w = f2bf(v.w);
  ((ushort4*)dst)[i4] = o;
}

// ------------------------------------------------- rmsnorm(x0), xm, x->bf16
__global__ __launch_bounds__(256) void k_rms_combine(const float* __restrict__ x,
                                                     const float* __restrict__ x0,
                                                     u16* __restrict__ xbf,
                                                     u16* __restrict__ xmbf) {
  int row = blockIdx.x;
  int tid = threadIdx.x, lane = tid & 63, w = tid >> 6;
  const float4* px0 = (const float4*)(x0 + (size_t)row * C_);
  const float4* px  = (const float4*)(x  + (size_t)row * C_);
  float4 v0 = px0[tid];
  float ss = v0.x * v0.x + v0.y * v0.y + v0.z * v0.z + v0.w * v0.w;
  #pragma unroll
  for (int m = 1; m < 64; m <<= 1) ss += __shfl_xor(ss, m, 64);
  __shared__ float red[4];
  if (lane == 0) red[w] = ss;
  __syncthreads();
  float tot = red[0] + red[1] + red[2] + red[3];
  float rn = rsqrtf(tot * (1.0f / C_) + EPS_);
  float4 vx = px[tid];
  ushort4 om, ox;
  om.x = f2bf(0.5f * (vx.x + v0.x * rn));
  om.y = f2bf(0.5f * (vx.y + v0.y * rn));
  om.z = f2bf(0.5f * (vx.z + v0.z * rn));
  om.w = f2bf(0.5f * (vx.w + v0.w * rn));
  ox.x = f2bf(vx.x); ox.y = f2bf(vx.y); ox.z = f2bf(vx.z); ox.w = f2bf(vx.w);
  ((ushort4*)(xmbf + (size_t)row * C_))[tid] = om;
  ((ushort4*)(xbf  + (size_t)row * C_))[tid] = ox;
}

// ------------------------------------------------------------- GEMM core
// m97 structure: 128x128 tile, BK=64, 4 waves each 64x64 (acc[4][4]),
// 2-barrier single-buffer, global_load_lds w16, swizzled ds_read_b128.
__device__ __forceinline__ void gemm_core(const u16* pa0, const u16* pb0,
                                          u16* Asl, u16* Bsl,
                                          int lane, int w, int r0, int c0,
                                          f32x4 acc[4][4]) {
  const char* Ab = (const char*)Asl;
  const char* Bb = (const char*)Bsl;
  for (int kt = 0; kt < 1024; kt += 64) {
    __syncthreads();
    #pragma unroll
    for (int c = 0; c < 4; c++) {
      gload16(pa0 + (size_t)c * 32 * 1024 + kt, Asl + (c * 32 + w * 8) * 64);
      gload16(pb0 + (size_t)c * 32 * 1024 + kt, Bsl + (c * 32 + w * 8) * 64);
    }
    __syncthreads();
    bf16x8 af[2][4], bfr[2][4];
    #pragma unroll
    for (int ks = 0; ks < 2; ks++)
      #pragma unroll
      for (int fi = 0; fi < 4; fi++) {
        af[ks][fi]  = *(const bf16x8*)(Ab + SWZ(r0 + fi * 16 + (lane & 15), ks * 4 + (lane >> 4)));
        bfr[ks][fi] = *(const bf16x8*)(Bb + SWZ(c0 + fi * 16 + (lane & 15), ks * 4 + (lane >> 4)));
      }
    #pragma unroll
    for (int ks = 0; ks < 2; ks++)
      #pragma unroll
      for (int fi = 0; fi < 4; fi++)
        #pragma unroll
        for (int fj = 0; fj < 4; fj++)
          acc[fi][fj] = __builtin_amdgcn_mfma_f32_16x16x32_bf16(af[ks][fi], bfr[ks][fj], acc[fi][fj], 0, 0, 0);
  }
}

// n-panels (BN=128): bn 0-7 q (Wq,xm); 8-9 k (Wk,xm); 10-11 v (Wv,xm);
// 12-13 v_init (Wv,x) -> f32 d_out.
__global__ __launch_bounds__(256) void k_gemm_qkv(const u16* __restrict__ xm,
                                                  const u16* __restrict__ xb,
                                                  const u16* __restrict__ Wq,
                                                  const u16* __restrict__ Wk,
                                                  const u16* __restrict__ Wv,
                                                  u16* __restrict__ qpre,
                                                  u16* __restrict__ kpre,
                                                  u16* __restrict__ vmid,
                                                  float* __restrict__ vinit) {
  __shared__ u16 Asl[128 * 64];
  __shared__ u16 Bsl[128 * 64];
  int tid = threadIdx.x, lane = tid & 63, w = tid >> 6;
  int m0 = blockIdx.x * 128, bn = blockIdx.y, n0 = bn * 128;
  const u16* A; const u16* Wseg; int nseg;
  if (bn < 8)       { A = xm; Wseg = Wq; nseg = n0; }
  else if (bn < 10) { A = xm; Wseg = Wk; nseg = n0 - 1024; }
  else if (bn < 12) { A = xm; Wseg = Wv; nseg = n0 - 1280; }
  else              { A = xb; Wseg = Wv; nseg = n0 - 1536; }
  int swo = SWO(lane);
  const u16* pa0 = A    + (size_t)(m0 + w * 8 + (lane >> 3)) * 1024 + swo;
  const u16* pb0 = Wseg + (size_t)(nseg + w * 8 + (lane >> 3)) * 1024 + swo;
  int r0 = (w & 1) * 64, c0 = (w >> 1) * 64;
  f32x4 acc[4][4] = {};
  gemm_core(pa0, pb0, Asl, Bsl, lane, w, r0, c0, acc);
  #pragma unroll
  for (int fi = 0; fi < 4; fi++)
    #pragma unroll
    for (int fj = 0; fj < 4; fj++)
      #pragma unroll
      for (int i = 0; i < 4; i++) {
        int mrow = m0 + r0 + fi * 16 + (lane >> 4) * 4 + i;
        int nl = nseg + c0 + fj * 16 + (lane & 15);
        float v = acc[fi][fj][i];
        if (bn < 8)       qpre[(size_t)mrow * 1024 + nl] = f2bf(v);
        else if (bn < 10) kpre[(size_t)mrow * 256 + nl] = f2bf(v);
        else if (bn < 12) vmid[(size_t)mrow * 256 + nl] = f2bf(v);
        else              vinit[(size_t)mrow * 256 + nl] = v;
      }
}

__global__ __launch_bounds__(256) void k_gemm_o(const u16* __restrict__ A,
                                                const u16* __restrict__ W,
                                                float* __restrict__ y) {
  __shared__ u16 Asl[128 * 64];
  __shared__ u16 Bsl[128 * 64];
  int tid = threadIdx.x, lane = tid & 63, w = tid >> 6;
  int m0 = blockIdx.x * 128, n0 = blockIdx.y * 128;
  int swo = SWO(lane);
  const u16* pa0 = A + (size_t)(m0 + w * 8 + (lane >> 3)) * 1024 + swo;
  const u16* pb0 = W + (size_t)(n0 + w * 8 + (lane >> 3)) * 1024 + swo;
  int r0 = (w & 1) * 64, c0 = (w >> 1) * 64;
  f32x4 acc[4][4] = {};
  gemm_core(pa0, pb0, Asl, Bsl, lane, w, r0, c0, acc);
  #pragma unroll
  for (int fi = 0; fi < 4; fi++)
    #pragma unroll
    for (int fj = 0; fj < 4; fj++)
      #pragma unroll
      for (int i = 0; i < 4; i++) {
        int mrow = m0 + r0 + fi * 16 + (lane >> 4) * 4 + i;
        int n = n0 + c0 + fj * 16 + (lane & 15);
        y[(size_t)mrow * 1024 + n] = acc[fi][fj][i];
      }
}

// ----------------------------------------- rope + rmsnorm on q,k heads
// Q scale: 1.2 * 0.125 = 0.15 (attention scale folded). K scale: 1.2.
__global__ __launch_bounds__(256) void k_qk_post(const u16* __restrict__ qpre,
                                                 const u16* __restrict__ kpre,
                                                 const float* __restrict__ cosp,
                                                 const float* __restrict__ sinp,
                                                 u16* __restrict__ Qh,
                                                 u16* __restrict__ Kh) {
  int w = threadIdx.x >> 6, lane = threadIdx.x & 63;
  int vid = blockIdx.x * 4 + w;
  const int NQ = B_ * T_ * NH_;
  int t; float val; size_t dst; u16* out; float scale;
  if (vid < NQ) {
    int h = vid & 15; t = (vid >> 4) & 2047; int b = vid >> 15;
    val = bf2f(qpre[(size_t)vid * 64 + lane]);
    dst = (((size_t)(b * NH_ + h) * T_) + t) * 64 + lane;
    out = Qh; scale = 0.15f;
  } else {
    int kid = vid - NQ;
    int hk = kid & 3; t = (kid >> 2) & 2047; int b = kid >> 13;
    val = bf2f(kpre[(size_t)kid * 64 + lane]);
    dst = (((size_t)(b * NKV_ + hk) * T_) + t) * 64 + lane;
    out = Kh; scale = 1.2f;
  }
  int di = lane & 31;
  float partner = __shfl_xor(val, 32, 64);
  float c = cosp[t * 32 + di], s = sinp[t * 32 + di];
  float r = (lane < 32) ? (val * c + partner * s) : (val * c - partner * s);
  float ss = r * r;
  #pragma unroll
  for (int m2 = 1; m2 < 64; m2 <<= 1) ss += __shfl_xor(ss, m2, 64);
  r *= rsqrtf(ss * (1.0f / 64.0f) + EPS_) * scale;
  out[dst] = f2bf(r);
}

// --------------------------------- V: add 0.5*ve, transpose to [b][hk][d][t]
__global__ __launch_bounds__(256) void k_vt(const u16* __restrict__ vmid,
                                            const float* __restrict__ ve,
                                            u16* __restrict__ VtG) {
  __shared__ u16 S[64][72];
  int tid = threadIdx.x;
  int t0 = blockIdx.x * 64, hk = blockIdx.y, b = blockIdx.z;
  {
    int tl = tid >> 2, dg = (tid & 3) * 16;
    const int4* pvm = (const int4*)(vmid + (size_t)(b * T_ + t0 + tl) * 256 + hk * 64 + dg);
    const float4* pve = (const float4*)(ve + ((size_t)(b * T_ + t0 + tl) * 4 + hk) * 64 + dg);
    int4 vv[2]; vv[0] = pvm[0]; vv[1] = pvm[1];
    const u16* vm = (const u16*)vv;
    float4 vf[4]; vf[0] = pve[0]; vf[1] = pve[1]; vf[2] = pve[2]; vf[3] = pve[3];
    const float* vfp = (const float*)vf;
    u16 r[16];
    #pragma unroll
    for (int e = 0; e < 16; e++) r[e] = f2bf(bf2f(vm[e]) + 0.5f * vfp[e]);
    *(int4*)&S[tl][dg] = *(int4*)&r[0];
    *(int4*)&S[tl][dg + 8] = *(int4*)&r[8];
  }
  __syncthreads();
  {
    int dl = tid >> 2, tg = (tid & 3) * 16;
    u16 r[16];
    #pragma unroll
    for (int j = 0; j < 16; j++) r[j] = S[tg + j][dl];
    u16* o = VtG + ((size_t)((b * NKV_ + hk) * 64 + dl)) * T_ + t0 + tg;
    *(int4*)&o[0] = *(int4*)&r[0];
    *(int4*)&o[8] = *(int4*)&r[8];
  }
}

// ---------------------------------------------------------------- attention
// Block = 2 waves = one 32-row q-tile; wave wv handles 32-key tiles
// klo + 32*wv, klo + 32*wv + 64, ... (interleaved). K/V frags global->reg
// (L2-resident), prefetch rotation, no barriers in main loop. Chunked
// end-merge through a ~4 KB LDS buffer (keeps total LDS ~5 KB so occupancy
// is VGPR-limited at 4 waves/SIMD, not LDS-limited).
// Task swizzle: bid&7 = (b*4+hk) -> XCD-aligned; longest q-tiles first.
__global__ __launch_bounds__(128, 4) void k_attn(const u16* __restrict__ Qh,
                                                 const u16* __restrict__ Kh,
                                                 const u16* __restrict__ VtG,
                                                 u16* __restrict__ ao) {
  __shared__ float OS[64][17];             // chunked o-merge staging (4.3 KB)
  __shared__ float Ml[2][32], Ll[2][32], Sc[2][32];
  int tid = threadIdx.x, lane = tid & 63, wv = tid >> 6;
  int hi = lane >> 5, qc = lane & 31;
  int bid = blockIdx.x;
  int g = bid & 7, within = bid >> 3;
  int b = g >> 2, hk = g & 3;
  int hq = within >> 6, qt = 63 - (within & 63);
  int h = hk * 4 + hq;
  int q0w = qt * 32;
  const u16* Qp = Qh + ((size_t)(b * NH_ + h) * T_ + q0w) * 64;
  const u16* Kp = Kh + ((size_t)(b * NKV_ + hk) * T_) * 64;
  const u16* Vp = VtG + ((size_t)(b * NKV_ + hk) * 64) * T_;

  // Q fragments (B-operand): qf[ds] = Q[q0w+qc][ds*16 + hi*8 .. +8]
  bf16x8 qf0 = *(const bf16x8*)(Qp + (size_t)qc * 64 + 0  + hi * 8);
  bf16x8 qf1 = *(const bf16x8*)(Qp + (size_t)qc * 64 + 16 + hi * 8);
  bf16x8 qf2 = *(const bf16x8*)(Qp + (size_t)qc * 64 + 32 + hi * 8);
  bf16x8 qf3 = *(const bf16x8*)(Qp + (size_t)qc * 64 + 48 + hi * 8);

  f32x16 o0 = {}, o1 = {};
  float m = -1e4f, l = 0.f;
  int klo = q0w - WIN_; if (klo < 0) klo = 0;
  int kt0 = klo + wv * 32;

  bf16x8 kf0, kf1, kf2, kf3, vf0, vf1, vf2, vf3;
  if (kt0 <= q0w) {
    const u16* kp = Kp + (size_t)(kt0 + qc) * 64 + hi * 8;
    kf0 = *(const bf16x8*)(kp + 0);  kf1 = *(const bf16x8*)(kp + 16);
    kf2 = *(const bf16x8*)(kp + 32); kf3 = *(const bf16x8*)(kp + 48);
    const u16* vp = Vp + (size_t)qc * T_ + kt0 + hi * 8;
    vf0 = *(const bf16x8*)(vp + 0);  vf1 = *(const bf16x8*)(vp + 16);
    vf2 = *(const bf16x8*)(vp + 32 * T_);  vf3 = *(const bf16x8*)(vp + 32 * T_ + 16);
  }

  for (int kt = kt0; kt <= q0w; kt += 64) {
    // S^T[key][q] = K * Q  (32 keys x 32 q, keys in rows)
    f32x16 st = {};
    __builtin_amdgcn_s_setprio(1);
    st = __builtin_amdgcn_mfma_f32_32x32x16_bf16(kf0, qf0, st, 0, 0, 0);
    st = __builtin_amdgcn_mfma_f32_32x32x16_bf16(kf1, qf1, st, 0, 0, 0);
    st = __builtin_amdgcn_mfma_f32_32x32x16_bf16(kf2, qf2, st, 0, 0, 0);
    st = __builtin_amdgcn_mfma_f32_32x32x16_bf16(kf3, qf3, st, 0, 0, 0);
    __builtin_amdgcn_s_setprio(0);
    int ktn = kt + 64;
    bool more = (ktn <= q0w);
    if (more) {   // prefetch next K tile into kf regs
      const u16* kp = Kp + (size_t)(ktn + qc) * 64 + hi * 8;
      kf0 = *(const bf16x8*)(kp + 0);  kf1 = *(const bf16x8*)(kp + 16);
      kf2 = *(const bf16x8*)(kp + 32); kf3 = *(const bf16x8*)(kp + 48);
    }
    // mask (boundary tiles only) + tile max
    bool full = (kt != q0w) && (kt != q0w - WIN_);
    float p[16];
    float tmax = -1e30f;
    int iq = q0w + qc;
    #pragma unroll
    for (int r = 0; r < 16; r++) {
      float sv = st[r];
      if (!full) {
        int j = kt + (r & 3) + 8 * (r >> 2) + 4 * hi;
        sv = (j <= iq && iq - j <= WIN_) ? sv : -1e9f;
      }
      p[r] = sv;
      tmax = fmaxf(tmax, sv);
    }
    tmax = fmaxf(tmax, __shfl_xor(tmax, 32, 64));
    // defer-max rescale (rare)
    if (__any(tmax > m + 8.0f)) {
      float mn = fmaxf(m, tmax);
      float al = __expf(m - mn);
      m = mn; l *= al;
      if (hi == 0) Sc[wv][qc] = al;
      #pragma unroll
      for (int r = 0; r < 16; r++) {
        float a2 = Sc[wv][(r & 3) + 8 * (r >> 2) + 4 * hi];
        o0[r] *= a2; o1[r] *= a2;
      }
    }
    // exp + row-sum + RTZ bf16 pack
    float rsum = 0.f;
    u32 pw[8];
    #pragma unroll
    for (int c = 0; c < 8; c++) {
      float pe = __expf(p[2 * c] - m);
      float po = __expf(p[2 * c + 1] - m);
      rsum += pe + po;
      pw[c] = __builtin_amdgcn_perm(__float_as_uint(po), __float_as_uint(pe), 0x07060302u);
    }
    rsum += __shfl_xor(rsum, 32, 64);
    l += rsum;
    // PV: build P A-frags via cross-half exchange, 2 k-groups of 16
    __builtin_amdgcn_s_setprio(1);
    #pragma unroll
    for (int ksp = 0; ksp < 2; ksp++) {
      union { u32 uw[4]; bf16x8 v; } U;
      #pragma unroll
      for (int c = 0; c < 2; c++) {
        u32 x = pw[4 * ksp + c];
        u32 y = pw[4 * ksp + 2 + c];
        u32 xs = (u32)__shfl_xor((int)x, 32, 64);
        u32 ys = (u32)__shfl_xor((int)y, 32, 64);
        U.uw[c]     = hi ? ys : x;
        U.uw[2 + c] = hi ? y : xs;
      }
      if (ksp == 0) {
        o0 = __builtin_amdgcn_mfma_f32_32x32x16_bf16(U.v, vf0, o0, 0, 0, 0);
        o1 = __builtin_amdgcn_mfma_f32_32x32x16_bf16(U.v, vf2, o1, 0, 0, 0);
      } else {
        o0 = __builtin_amdgcn_mfma_f32_32x32x16_bf16(U.v, vf1, o0, 0, 0, 0);
        o1 = __builtin_amdgcn_mfma_f32_32x32x16_bf16(U.v, vf3, o1, 0, 0, 0);
      }
    }
    __builtin_amdgcn_s_setprio(0);
    if (more) {   // prefetch next V tile
      const u16* vp = Vp + (size_t)qc * T_ + ktn + hi * 8;
      vf0 = *(const bf16x8*)(vp + 0);  vf1 = *(const bf16x8*)(vp + 16);
      vf2 = *(const bf16x8*)(vp + 32 * T_);  vf3 = *(const bf16x8*)(vp + 32 * T_ + 16);
    }
  }

  // ---- chunked merge of the two window halves (small LDS) ----
  if (hi == 0) { Ml[wv][qc] = m; Ll[wv][qc] = l; }
  __syncthreads();
  // per-r combined scale for THIS wave: s_wv(q) / (l0*s0 + l1*s1)
  float sfac[16];
  #pragma unroll
  for (int r = 0; r < 16; r++) {
    int q = (r & 3) + 8 * (r >> 2) + 4 * hi;
    float m0v = Ml[0][q], m1v = Ml[1][q];
    float l0v = Ll[0][q], l1v = Ll[1][q];
    float ms = fmaxf(m0v, m1v);
    float s0 = __expf(m0v - ms), s1 = __expf(m1v - ms);
    float inv = 1.0f / (l0v * s0 + l1v * s1);
    sfac[r] = (wv == 0 ? s0 : s1) * inv;
  }
  if (wv == 1) {
    #pragma unroll
    for (int r = 0; r < 16; r++) OS[lane][r] = o0[r] * sfac[r];
  }
  __syncthreads();
  if (wv == 0) {
    #pragma unroll
    for (int r = 0; r < 16; r++) {
      int q = (r & 3) + 8 * (r >> 2) + 4 * hi;
      size_t base = ((size_t)(b * T_ + q0w + q) * NH_ + h) * 64;
      ao[base + qc] = f2bf(o0[r] * sfac[r] + OS[lane][r]);
    }
  }
  __syncthreads();
  if (wv == 1) {
    #pragma unroll
    for (int r = 0; r < 16; r++) OS[lane][r] = o1[r] * sfac[r];
  }
  __syncthreads();
  if (wv == 0) {
    #pragma unroll
    for (int r = 0; r < 16; r++) {
      int q = (r & 3) + 8 * (r >> 2) + 4 * hi;
      size_t base = ((size_t)(b * T_ + q0w + q) * NH_ + h) * 64;
      ao[base + 32 + qc] = f2bf(o1[r] * sfac[r] + OS[lane][r]);
    }
  }
}

// ---------------------------------------------------------------------------
extern "C" void kernel_launch(void* const* d_in, const int* in_sizes, int n_in,
                              void* d_out, int out_size, void* d_ws, size_t ws_size,
                              hipStream_t stream) {
  const float* x    = (const float*)d_in[0];
  const float* x0   = (const float*)d_in[1];
  const float* ve   = (const float*)d_in[2];
  const float* cosp = (const float*)d_in[3];
  const float* sinp = (const float*)d_in[4];
  const float* Wq   = (const float*)d_in[5];
  const float* Wk   = (const float*)d_in[6];
  const float* Wv   = (const float*)d_in[7];
  const float* Wo   = (const float*)d_in[8];
  float* out = (float*)d_out;

  u16* ws = (u16*)d_ws;
  size_t off = 0;
  u16* xbf  = ws + off; off += (size_t)M_ * C_;       // also ao
  u16* xmbf = ws + off; off += (size_t)M_ * C_;       // also Qh
  u16* Wqb  = ws + off; off += (size_t)1024 * 1024;   // also Kh
  u16* Wkb  = ws + off; off += (size_t)256 * 1024;
  u16* Wvb  = ws + off; off += (size_t)256 * 1024;
  u16* Wob  = ws + off; off += (size_t)1024 * 1024;
  u16* qpre = ws + off; off += (size_t)M_ * 1024;
  u16* kpre = ws + off; off += (size_t)M_ * 256;
  u16* vmid = ws + off; off += (size_t)M_ * 256;
  u16* VtG  = ws + off; off += (size_t)B_ * NKV_ * 64 * T_;
  u16* aob = xbf;
  u16* Qhb = xmbf;
  u16* Khb = Wqb;

  k_convert_all<<<2560, 256, 0, stream>>>(Wq, Wk, Wv, Wo, Wqb);
  k_rms_combine<<<4096, 256, 0, stream>>>(x, x0, xbf, xmbf);
  k_gemm_qkv<<<dim3(32, 14), 256, 0, stream>>>(xmbf, xbf, Wqb, Wkb, Wvb,
                                               qpre, kpre, vmid, out + (size_t)M_ * C_);
  k_qk_post<<<20480, 256, 0, stream>>>(qpre, kpre, cosp, sinp, Qhb, Khb);
  k_vt<<<dim3(32, 4, 2), 256, 0, stream>>>(vmid, ve, VtG);
  k_attn<<<2048, 128, 0, stream>>>(Qhb, Khb, VtG, aob);
  k_gemm_o<<<dim3(32, 8), 256, 0, stream>>>(aob, Wob, out);
}